// Round 10
// baseline (126.798 us; speedup 1.0000x reference)
//
#include <hip/hip_runtime.h>
#include <hip/hip_bf16.h>
#include <math.h>

#define BATCH      2048
#define IN_DIM     784
#define HIDDEN     512
#define STYLE      128
#define NUM_LABELS 10
#define FC1_STRIDE ((IN_DIM + 1) * HIDDEN)   // 785*512
#define FC2_STRIDE ((HIDDEN + 1) * STYLE)    // 513*128
#define KP1        832                        // IN_DIM padded to mult of 64
#define TB         64
#define BK         64
#define MAX_TILES  48    // >= max possible sum(ceil(c_L/64)) = 41

// ---- meta (int) layout at d_ws byte 0 ----
#define META_NTILES 31
#define META_TILES  32     // 3 ints per tile: label,pstart,nrows
#define META_PERM   176

// ---- workspace layout: meta + h1b only (w1b/w2b/xb eliminated in r9) ----
#define H1B_OFF  16384ULL                               // [2048][512] bf16 (permuted rows)
#define WS_NEED  (H1B_OFF + (size_t)BATCH*HIDDEN*2)     // ~2.1 MB

typedef short short8  __attribute__((ext_vector_type(8)));
typedef float float4e __attribute__((ext_vector_type(4)));

__device__ __forceinline__ ushort f2b(float v) {
    __hip_bfloat16 h = __float2bfloat16(v);
    return *reinterpret_cast<ushort*>(&h);
}

// =======================================================================
// meta: 1 block, ballot-based counting sort (verified correct in r1/r8).
// No weight conversion dispatch anymore — weights convert inline in GEMMs.
// =======================================================================
__global__ void k_meta(const int* __restrict__ m, int* __restrict__ meta) {
    const int tid = threadIdx.x;
    const int lane = tid & 63, wv = tid >> 6;

    __shared__ int chunkCnt[32][NUM_LABELS];
    __shared__ int chunkPre[32][NUM_LABELS];
    __shared__ int labCnt[NUM_LABELS];
    __shared__ int labOff[NUM_LABELS + 1];

    for (int c = wv; c < 32; c += 4) {
        int L = m[c * 64 + lane];
#pragma unroll
        for (int L0 = 0; L0 < NUM_LABELS; ++L0) {
            unsigned long long mk = __ballot(L == L0);
            if (lane == L0) chunkCnt[c][L0] = __popcll(mk);
        }
    }
    __syncthreads();
    if (tid < NUM_LABELS) {
        int run = 0;
        for (int c = 0; c < 32; ++c) { chunkPre[c][tid] = run; run += chunkCnt[c][tid]; }
        labCnt[tid] = run;
    }
    __syncthreads();
    if (tid == 0) {
        int off = 0;
        for (int L = 0; L < NUM_LABELS; ++L) { labOff[L] = off; off += labCnt[L]; }
        labOff[NUM_LABELS] = off;
        int idx = 0;
        for (int L = 0; L < NUM_LABELS; ++L) {
            int c = labCnt[L], o = labOff[L];
            for (int t = 0; t < c; t += TB) {
                meta[META_TILES + idx * 3 + 0] = L;
                meta[META_TILES + idx * 3 + 1] = o + t;
                meta[META_TILES + idx * 3 + 2] = min(TB, c - t);
                ++idx;
            }
        }
        meta[META_NTILES] = idx;
    }
    __syncthreads();
    for (int c = wv; c < 32; c += 4) {
        int b = c * 64 + lane;
        int L = m[b];
#pragma unroll
        for (int L0 = 0; L0 < NUM_LABELS; ++L0) {
            unsigned long long mk = __ballot(L == L0);
            if (L == L0) {
                int r = __popcll(mk & ((1ull << lane) - 1ull));
                meta[META_PERM + labOff[L0] + chunkPre[c][L0] + r] = b;
            }
        }
    }
}

// =======================================================================
// fc1: bf16 MFMA, BK=64, LDS double-buffer.
// A: fp32 x rows, f2b at stage time (round-0 proven path).
// B: INLINE transpose+convert from fp32 fc1t [k][n] — thread (sr,sc)
//    reads 16 fp32 at (k0+sc*16+j)*512 + col0+sr (64B coalesced runs
//    across sr lanes), converts via f2b, stores to the SAME Bs slots as
//    the old w1b path → bitwise-identical fragments.
// =======================================================================
__launch_bounds__(256)
__global__ void k_fc1c(const float* __restrict__ x, const float* __restrict__ fc1t,
                       const int* __restrict__ meta, ushort* __restrict__ h1b) {
    const int t = blockIdx.x;
    if (t >= meta[META_NTILES]) return;
    const int L      = meta[META_TILES + 3 * t + 0];
    const int pstart = meta[META_TILES + 3 * t + 1];
    const int nrows  = meta[META_TILES + 3 * t + 2];
    const int col0   = blockIdx.y * 64;
    const float* __restrict__ Wf = fc1t + (size_t)L * FC1_STRIDE;

    __shared__ int rows[TB];
    __shared__ __align__(16) ushort As[2][64][72];
    __shared__ __align__(16) ushort Bs[2][64][72];

    const int tid = threadIdx.x;
    if (tid < TB) rows[tid] = (tid < nrows) ? meta[META_PERM + pstart + tid] : -1;
    __syncthreads();

    const int sr = tid >> 2, sc = tid & 3;
    const int lane = tid & 63, wv = tid >> 6;
    const int qd = lane >> 4, ln16 = lane & 15;

    const int arow = rows[sr];
    const bool aval = (arow >= 0);
    const float* __restrict__ xr = x + (size_t)(aval ? arow : 0) * IN_DIM;
    const float* __restrict__ wcol = Wf + col0 + sr;   // column (col0+sr) of [k][n]

    float4e acc[4] = {};
    float4 a0, a1, a2, a3;
    float bl[16];

    // ---- chunk 0 -> buf 0 (direct) ----
    {
        const int ka = sc * 16;
        a0 = make_float4(0.f,0.f,0.f,0.f); a1 = a0; a2 = a0; a3 = a0;
        if (aval) {
            if (ka      < IN_DIM) a0 = *(const float4*)(xr + ka);
            if (ka + 4  < IN_DIM) a1 = *(const float4*)(xr + ka + 4);
            if (ka + 8  < IN_DIM) a2 = *(const float4*)(xr + ka + 8);
            if (ka + 12 < IN_DIM) a3 = *(const float4*)(xr + ka + 12);
        }
#pragma unroll
        for (int j = 0; j < 16; ++j) {
            int kk = sc * 16 + j;
            bl[j] = (kk < IN_DIM) ? wcol[(size_t)kk * HIDDEN] : 0.f;
        }
        ushort av[16];
        av[0]=f2b(a0.x); av[1]=f2b(a0.y); av[2]=f2b(a0.z); av[3]=f2b(a0.w);
        av[4]=f2b(a1.x); av[5]=f2b(a1.y); av[6]=f2b(a1.z); av[7]=f2b(a1.w);
        av[8]=f2b(a2.x); av[9]=f2b(a2.y); av[10]=f2b(a2.z); av[11]=f2b(a2.w);
        av[12]=f2b(a3.x); av[13]=f2b(a3.y); av[14]=f2b(a3.z); av[15]=f2b(a3.w);
        ushort bv[16];
#pragma unroll
        for (int j = 0; j < 16; ++j) bv[j] = f2b(bl[j]);
        *(uint4*)&As[0][sr][sc * 16 + 0] = *(const uint4*)&av[0];
        *(uint4*)&As[0][sr][sc * 16 + 8] = *(const uint4*)&av[8];
        *(uint4*)&Bs[0][sr][sc * 16 + 0] = *(const uint4*)&bv[0];
        *(uint4*)&Bs[0][sr][sc * 16 + 8] = *(const uint4*)&bv[8];
    }
    // ---- chunk 1 -> regs ----
    {
        const int ka = BK + sc * 16;
        a0 = make_float4(0.f,0.f,0.f,0.f); a1 = a0; a2 = a0; a3 = a0;
        if (aval) {
            if (ka      < IN_DIM) a0 = *(const float4*)(xr + ka);
            if (ka + 4  < IN_DIM) a1 = *(const float4*)(xr + ka + 4);
            if (ka + 8  < IN_DIM) a2 = *(const float4*)(xr + ka + 8);
            if (ka + 12 < IN_DIM) a3 = *(const float4*)(xr + ka + 12);
        }
#pragma unroll
        for (int j = 0; j < 16; ++j) {
            int kk = BK + sc * 16 + j;
            bl[j] = (kk < IN_DIM) ? wcol[(size_t)kk * HIDDEN] : 0.f;
        }
    }

    int p = 0;
    for (int k0 = 0; k0 < KP1; k0 += BK) {
        __syncthreads();
        if (k0 + BK < KP1) {
            ushort av[16];
            av[0]=f2b(a0.x); av[1]=f2b(a0.y); av[2]=f2b(a0.z); av[3]=f2b(a0.w);
            av[4]=f2b(a1.x); av[5]=f2b(a1.y); av[6]=f2b(a1.z); av[7]=f2b(a1.w);
            av[8]=f2b(a2.x); av[9]=f2b(a2.y); av[10]=f2b(a2.z); av[11]=f2b(a2.w);
            av[12]=f2b(a3.x); av[13]=f2b(a3.y); av[14]=f2b(a3.z); av[15]=f2b(a3.w);
            ushort bv[16];
#pragma unroll
            for (int j = 0; j < 16; ++j) bv[j] = f2b(bl[j]);
            *(uint4*)&As[1-p][sr][sc * 16 + 0] = *(const uint4*)&av[0];
            *(uint4*)&As[1-p][sr][sc * 16 + 8] = *(const uint4*)&av[8];
            *(uint4*)&Bs[1-p][sr][sc * 16 + 0] = *(const uint4*)&bv[0];
            *(uint4*)&Bs[1-p][sr][sc * 16 + 8] = *(const uint4*)&bv[8];
        }
        if (k0 + 2*BK < KP1) {
            const int ka = k0 + 2*BK + sc * 16;
            a0 = make_float4(0.f,0.f,0.f,0.f); a1 = a0; a2 = a0; a3 = a0;
            if (aval) {
                if (ka      < IN_DIM) a0 = *(const float4*)(xr + ka);
                if (ka + 4  < IN_DIM) a1 = *(const float4*)(xr + ka + 4);
                if (ka + 8  < IN_DIM) a2 = *(const float4*)(xr + ka + 8);
                if (ka + 12 < IN_DIM) a3 = *(const float4*)(xr + ka + 12);
            }
#pragma unroll
            for (int j = 0; j < 16; ++j) {
                int kk = k0 + 2*BK + sc * 16 + j;
                bl[j] = (kk < IN_DIM) ? wcol[(size_t)kk * HIDDEN] : 0.f;
            }
        }
#pragma unroll
        for (int s = 0; s < 2; ++s) {
            short8 af = *(const short8*)&As[p][wv * 16 + ln16][s * 32 + qd * 8];
#pragma unroll
            for (int nt = 0; nt < 4; ++nt) {
                short8 bf = *(const short8*)&Bs[p][nt * 16 + ln16][s * 32 + qd * 8];
                acc[nt] = __builtin_amdgcn_mfma_f32_16x16x32_bf16(af, bf, acc[nt], 0, 0, 0);
            }
        }
        p ^= 1;
    }

    const float* __restrict__ bias = fc1t + (size_t)L * FC1_STRIDE + (size_t)IN_DIM * HIDDEN + col0;
#pragma unroll
    for (int nt = 0; nt < 4; ++nt) {
        const int c = nt * 16 + ln16;
        const float bs = bias[c];
#pragma unroll
        for (int i = 0; i < 4; ++i) {
            const int r = wv * 16 + qd * 4 + i;
            if (r < nrows)
                h1b[(size_t)(pstart + r) * HIDDEN + col0 + c] = f2b(fmaxf(acc[nt][i] + bs, 0.f));
        }
    }
}

// =======================================================================
// fc2: bf16 MFMA, BK=64, LDS double-buffer.
// A: h1b bf16 (unchanged). B: INLINE transpose+convert from fp32 fc2t.
// =======================================================================
__launch_bounds__(256)
__global__ void k_fc2c(const ushort* __restrict__ h1b, const float* __restrict__ fc2t,
                       const int* __restrict__ meta, float* __restrict__ out) {
    const int t = blockIdx.x;
    if (t >= meta[META_NTILES]) return;
    const int L      = meta[META_TILES + 3 * t + 0];
    const int pstart = meta[META_TILES + 3 * t + 1];
    const int nrows  = meta[META_TILES + 3 * t + 2];
    const int col0   = blockIdx.y * 64;
    const float* __restrict__ Wf = fc2t + (size_t)L * FC2_STRIDE;

    __shared__ int rows[TB];
    __shared__ __align__(16) ushort As[2][64][72];
    __shared__ __align__(16) ushort Bs[2][64][72];

    const int tid = threadIdx.x;
    if (tid < TB) rows[tid] = (tid < nrows) ? meta[META_PERM + pstart + tid] : -1;
    __syncthreads();

    const int sr = tid >> 2, sc = tid & 3;
    const int lane = tid & 63, wv = tid >> 6;
    const int qd = lane >> 4, ln16 = lane & 15;

    const bool aval = (sr < nrows);
    const uint4* __restrict__ agp = (const uint4*)(h1b + (size_t)(pstart + (aval ? sr : 0)) * HIDDEN);
    const float* __restrict__ wcol = Wf + col0 + sr;   // column (col0+sr) of [k][n]

    float4e acc[4] = {};
    uint4 a0, a1;
    float bl[16];

    // chunk 0 -> buf 0
    a0 = make_uint4(0u,0u,0u,0u); a1 = a0;
    if (aval) { a0 = agp[sc * 2 + 0]; a1 = agp[sc * 2 + 1]; }
#pragma unroll
    for (int j = 0; j < 16; ++j) bl[j] = wcol[(size_t)(sc * 16 + j) * STYLE];
    {
        ushort bv[16];
#pragma unroll
        for (int j = 0; j < 16; ++j) bv[j] = f2b(bl[j]);
        *(uint4*)&As[0][sr][sc * 16 + 0] = a0;
        *(uint4*)&As[0][sr][sc * 16 + 8] = a1;
        *(uint4*)&Bs[0][sr][sc * 16 + 0] = *(const uint4*)&bv[0];
        *(uint4*)&Bs[0][sr][sc * 16 + 8] = *(const uint4*)&bv[8];
    }
    // chunk 1 -> regs
    {
        const int base = (BK >> 3) + sc * 2;
        a0 = make_uint4(0u,0u,0u,0u); a1 = a0;
        if (aval) { a0 = agp[base]; a1 = agp[base + 1]; }
#pragma unroll
        for (int j = 0; j < 16; ++j) bl[j] = wcol[(size_t)(BK + sc * 16 + j) * STYLE];
    }

    int p = 0;
    for (int k0 = 0; k0 < HIDDEN; k0 += BK) {
        __syncthreads();
        if (k0 + BK < HIDDEN) {
            ushort bv[16];
#pragma unroll
            for (int j = 0; j < 16; ++j) bv[j] = f2b(bl[j]);
            *(uint4*)&As[1-p][sr][sc * 16 + 0] = a0;
            *(uint4*)&As[1-p][sr][sc * 16 + 8] = a1;
            *(uint4*)&Bs[1-p][sr][sc * 16 + 0] = *(const uint4*)&bv[0];
            *(uint4*)&Bs[1-p][sr][sc * 16 + 8] = *(const uint4*)&bv[8];
        }
        if (k0 + 2*BK < HIDDEN) {
            const int base = ((k0 + 2*BK) >> 3) + sc * 2;
            a0 = make_uint4(0u,0u,0u,0u); a1 = a0;
            if (aval) { a0 = agp[base]; a1 = agp[base + 1]; }
#pragma unroll
            for (int j = 0; j < 16; ++j) bl[j] = wcol[(size_t)(k0 + 2*BK + sc * 16 + j) * STYLE];
        }
#pragma unroll
        for (int s = 0; s < 2; ++s) {
            short8 af = *(const short8*)&As[p][wv * 16 + ln16][s * 32 + qd * 8];
#pragma unroll
            for (int nt = 0; nt < 4; ++nt) {
                short8 bf = *(const short8*)&Bs[p][nt * 16 + ln16][s * 32 + qd * 8];
                acc[nt] = __builtin_amdgcn_mfma_f32_16x16x32_bf16(af, bf, acc[nt], 0, 0, 0);
            }
        }
        p ^= 1;
    }

    const float* __restrict__ bias = fc2t + (size_t)L * FC2_STRIDE + (size_t)HIDDEN * STYLE + col0;
#pragma unroll
    for (int nt = 0; nt < 4; ++nt) {
        const int c = nt * 16 + ln16;
        const float bs = bias[c];
#pragma unroll
        for (int i = 0; i < 4; ++i) {
            const int r = wv * 16 + qd * 4 + i;
            if (r < nrows) {
                const int orow = rows[r];
                out[(size_t)orow * STYLE + col0 + c] = 1.f / (1.f + __expf(-(acc[nt][i] + bs)));
            }
        }
    }
}

// ---------- fallback (ws too small): fused per-row, slow but correct ----------
__launch_bounds__(256)
__global__ void k_naive(const float* __restrict__ x, const int* __restrict__ m,
                        const float* __restrict__ fc1t, const float* __restrict__ fc2t,
                        float* __restrict__ out) {
    __shared__ float xs[IN_DIM];
    __shared__ float h1[HIDDEN];
    const int b = blockIdx.x, tid = threadIdx.x, L = m[b];
    for (int k = tid; k < IN_DIM; k += 256) xs[k] = x[(size_t)b * IN_DIM + k];
    __syncthreads();
    const float* __restrict__ W1 = fc1t + (size_t)L * FC1_STRIDE;
    for (int j = tid; j < HIDDEN; j += 256) {
        float acc = W1[(size_t)IN_DIM * HIDDEN + j];
        for (int k = 0; k < IN_DIM; ++k) acc = fmaf(xs[k], W1[(size_t)k * HIDDEN + j], acc);
        h1[j] = fmaxf(acc, 0.f);
    }
    __syncthreads();
    const float* __restrict__ W2 = fc2t + (size_t)L * FC2_STRIDE;
    for (int j = tid; j < STYLE; j += 256) {
        float acc = W2[(size_t)HIDDEN * STYLE + j];
        for (int k = 0; k < HIDDEN; ++k) acc = fmaf(h1[k], W2[(size_t)k * STYLE + j], acc);
        out[(size_t)b * STYLE + j] = 1.f / (1.f + __expf(-acc));
    }
}

extern "C" void kernel_launch(void* const* d_in, const int* in_sizes, int n_in,
                              void* d_out, int out_size, void* d_ws, size_t ws_size,
                              hipStream_t stream) {
    const float* x    = (const float*)d_in[0];
    const int*   m    = (const int*)d_in[1];
    const float* fc1t = (const float*)d_in[2];
    const float* fc2t = (const float*)d_in[3];
    float* out = (float*)d_out;

    if (ws_size >= WS_NEED) {
        int*    meta = (int*)d_ws;
        ushort* h1b  = (ushort*)((char*)d_ws + H1B_OFF);

        k_meta<<<1, 256, 0, stream>>>(m, meta);
        k_fc1c<<<dim3(MAX_TILES, HIDDEN / 64), 256, 0, stream>>>(x, fc1t, meta, h1b);
        k_fc2c<<<dim3(MAX_TILES, STYLE / 64), 256, 0, stream>>>(h1b, fc2t, meta, out);
    } else {
        k_naive<<<BATCH, 256, 0, stream>>>(x, m, fc1t, fc2t, out);
    }
}

// Round 12
// 107.783 us; speedup vs baseline: 1.1764x; 1.1764x over previous
//
#include <hip/hip_runtime.h>
#include <hip/hip_bf16.h>
#include <math.h>

#define BATCH      2048
#define IN_DIM     784
#define HIDDEN     512
#define STYLE      128
#define NUM_LABELS 10
#define FC1_STRIDE ((IN_DIM + 1) * HIDDEN)   // 785*512
#define FC2_STRIDE ((HIDDEN + 1) * STYLE)    // 513*128
#define KP1        832                        // IN_DIM padded to mult of 64
#define TB         64
#define BK         64
#define MAX_TILES  48    // >= max possible sum(ceil(c_L/64)) = 41

// ---- meta (int) layout at d_ws byte 0 ----
#define META_NTILES 31
#define META_TILES  32     // 3 ints per tile: label,pstart,nrows
#define META_PERM   176

// ---- bf16 workspace layout (byte offsets) — r0 layout, no xb ----
#define W1B_OFF  16384ULL                               // [10][512][832] bf16 ([L][n][k])
#define W2B_OFF  (W1B_OFF + 10ULL*HIDDEN*KP1*2)         // [10][128][512] bf16 ([L][n][k])
#define H1B_OFF  (W2B_OFF + 10ULL*STYLE*HIDDEN*2)       // [2048][512] bf16 (permuted rows)
#define WS_NEED  (H1B_OFF + (size_t)BATCH*HIDDEN*2)     // ~11.9 MB

#define W1_KB 26                                        // 832/32
#define W1_NB 16                                        // 512/32
#define W2_KB 16                                        // 512/32
#define W2_NB 4                                         // 128/32
#define W1_BLOCKS (W1_KB*W1_NB*NUM_LABELS)              // 4160
#define W2_BLOCKS (W2_KB*W2_NB*NUM_LABELS)              // 640

typedef short short8  __attribute__((ext_vector_type(8)));
typedef float float4e __attribute__((ext_vector_type(4)));

__device__ __forceinline__ ushort f2b(float v) {
    __hip_bfloat16 h = __float2bfloat16(v);
    return *reinterpret_cast<ushort*>(&h);
}

// =======================================================================
// prep: block 0 = ballot-sort meta (verified r8); blocks 1..4800 = weight
// transpose+convert (verified r0/r8). No xb (r8 measured it as regression).
// =======================================================================
__global__ void k_prep(const int* __restrict__ m, const float* __restrict__ fc1t,
                       const float* __restrict__ fc2t, int* __restrict__ meta,
                       ushort* __restrict__ w1b, ushort* __restrict__ w2b) {
    const int tid = threadIdx.x;
    int bid = blockIdx.x;
    const int lane = tid & 63, wv = tid >> 6;

    __shared__ union __align__(16) {
        float tile[32][33];
        struct {
            int chunkCnt[32][NUM_LABELS];
            int chunkPre[32][NUM_LABELS];
            int labCnt[NUM_LABELS];
            int labOff[NUM_LABELS + 1];
        } mt;
    } sm;

    if (bid == 0) {
        for (int c = wv; c < 32; c += 4) {
            int L = m[c * 64 + lane];
#pragma unroll
            for (int L0 = 0; L0 < NUM_LABELS; ++L0) {
                unsigned long long mk = __ballot(L == L0);
                if (lane == L0) sm.mt.chunkCnt[c][L0] = __popcll(mk);
            }
        }
        __syncthreads();
        if (tid < NUM_LABELS) {
            int run = 0;
            for (int c = 0; c < 32; ++c) { sm.mt.chunkPre[c][tid] = run; run += sm.mt.chunkCnt[c][tid]; }
            sm.mt.labCnt[tid] = run;
        }
        __syncthreads();
        if (tid == 0) {
            int off = 0;
            for (int L = 0; L < NUM_LABELS; ++L) { sm.mt.labOff[L] = off; off += sm.mt.labCnt[L]; }
            sm.mt.labOff[NUM_LABELS] = off;
            int idx = 0;
            for (int L = 0; L < NUM_LABELS; ++L) {
                int c = sm.mt.labCnt[L], o = sm.mt.labOff[L];
                for (int t = 0; t < c; t += TB) {
                    meta[META_TILES + idx * 3 + 0] = L;
                    meta[META_TILES + idx * 3 + 1] = o + t;
                    meta[META_TILES + idx * 3 + 2] = min(TB, c - t);
                    ++idx;
                }
            }
            meta[META_NTILES] = idx;
        }
        __syncthreads();
        for (int c = wv; c < 32; c += 4) {
            int b = c * 64 + lane;
            int L = m[b];
#pragma unroll
            for (int L0 = 0; L0 < NUM_LABELS; ++L0) {
                unsigned long long mk = __ballot(L == L0);
                if (L == L0) {
                    int r = __popcll(mk & ((1ull << lane) - 1ull));
                    meta[META_PERM + sm.mt.labOff[L0] + sm.mt.chunkPre[c][L0] + r] = b;
                }
            }
        }
        return;
    }

    bid -= 1;
    const float* src; ushort* dst; int Kvalid, Kpad, N, kb, nb, L; size_t srcL, dstL;
    if (bid < W1_BLOCKS) {
        kb = bid % W1_KB; nb = (bid / W1_KB) % W1_NB; L = bid / (W1_KB * W1_NB);
        src = fc1t; dst = w1b; Kvalid = IN_DIM; Kpad = KP1; N = HIDDEN;
        srcL = FC1_STRIDE; dstL = (size_t)HIDDEN * KP1;
    } else {
        bid -= W1_BLOCKS;
        kb = bid % W2_KB; nb = (bid / W2_KB) % W2_NB; L = bid / (W2_KB * W2_NB);
        src = fc2t; dst = w2b; Kvalid = HIDDEN; Kpad = HIDDEN; N = STYLE;
        srcL = FC2_STRIDE; dstL = (size_t)STYLE * HIDDEN;
    }
    const int tx = tid & 31, ty = tid >> 5;
    const int k0 = kb * 32, n0 = nb * 32;
    for (int r = ty; r < 32; r += 8) {
        int k = k0 + r;
        sm.tile[r][tx] = (k < Kvalid) ? src[(size_t)L * srcL + (size_t)k * N + n0 + tx] : 0.f;
    }
    __syncthreads();
    for (int r = ty; r < 32; r += 8) {
        int n = n0 + r;
        dst[(size_t)L * dstL + (size_t)n * Kpad + k0 + tx] = f2b(sm.tile[tx][r]);
    }
}

// =======================================================================
// fc1: 64-row x 32-col tiles (16 col-panels -> 768 blocks, ~2.5 blk/CU vs
// r0's ~1.3: the occupancy-11% latency-bound fix from r10 counters).
// A: fp32 x rows, f2b at stage (r0 proven). B: bf16 w1b, 1 uint4/thread.
// =======================================================================
__launch_bounds__(256)
__global__ void k_fc1m(const float* __restrict__ x, const ushort* __restrict__ w1b,
                       const float* __restrict__ fc1t, const int* __restrict__ meta,
                       ushort* __restrict__ h1b) {
    const int t = blockIdx.x;
    if (t >= meta[META_NTILES]) return;
    const int L      = meta[META_TILES + 3 * t + 0];
    const int pstart = meta[META_TILES + 3 * t + 1];
    const int nrows  = meta[META_TILES + 3 * t + 2];
    const int col0   = blockIdx.y * 32;
    const ushort* __restrict__ W = w1b + (size_t)L * HIDDEN * KP1 + (size_t)col0 * KP1;

    __shared__ int rows[TB];
    __shared__ __align__(16) ushort As[2][64][72];
    __shared__ __align__(16) ushort Bs[2][32][72];

    const int tid = threadIdx.x;
    if (tid < TB) rows[tid] = (tid < nrows) ? meta[META_PERM + pstart + tid] : -1;
    __syncthreads();

    const int sr = tid >> 2, sc = tid & 3;     // A staging: 64 rows x 4 seg
    const int sb = tid >> 3, scb = tid & 7;    // B staging: 32 cols x 8 seg
    const int lane = tid & 63, wv = tid >> 6;
    const int qd = lane >> 4, ln16 = lane & 15;

    const int arow = rows[sr];
    const bool aval = (arow >= 0);
    const float* __restrict__ xr = x + (size_t)(aval ? arow : 0) * IN_DIM;
    const uint4* __restrict__ bgp = (const uint4*)(W + (size_t)sb * KP1);

    float4e acc[2] = {};
    float4 a0, a1, a2, a3;
    uint4 b0;

    // ---- chunk 0 -> buf 0 ----
    {
        const int ka = sc * 16;
        a0 = make_float4(0.f,0.f,0.f,0.f); a1 = a0; a2 = a0; a3 = a0;
        if (aval) {
            if (ka      < IN_DIM) a0 = *(const float4*)(xr + ka);
            if (ka + 4  < IN_DIM) a1 = *(const float4*)(xr + ka + 4);
            if (ka + 8  < IN_DIM) a2 = *(const float4*)(xr + ka + 8);
            if (ka + 12 < IN_DIM) a3 = *(const float4*)(xr + ka + 12);
        }
        b0 = bgp[scb];
        ushort av[16];
        av[0]=f2b(a0.x); av[1]=f2b(a0.y); av[2]=f2b(a0.z); av[3]=f2b(a0.w);
        av[4]=f2b(a1.x); av[5]=f2b(a1.y); av[6]=f2b(a1.z); av[7]=f2b(a1.w);
        av[8]=f2b(a2.x); av[9]=f2b(a2.y); av[10]=f2b(a2.z); av[11]=f2b(a2.w);
        av[12]=f2b(a3.x); av[13]=f2b(a3.y); av[14]=f2b(a3.z); av[15]=f2b(a3.w);
        *(uint4*)&As[0][sr][sc * 16 + 0] = *(const uint4*)&av[0];
        *(uint4*)&As[0][sr][sc * 16 + 8] = *(const uint4*)&av[8];
        *(uint4*)&Bs[0][sb][scb * 8]     = b0;
    }
    // ---- chunk 1 -> regs ----
    {
        const int ka = BK + sc * 16;
        a0 = make_float4(0.f,0.f,0.f,0.f); a1 = a0; a2 = a0; a3 = a0;
        if (aval) {
            if (ka      < IN_DIM) a0 = *(const float4*)(xr + ka);
            if (ka + 4  < IN_DIM) a1 = *(const float4*)(xr + ka + 4);
            if (ka + 8  < IN_DIM) a2 = *(const float4*)(xr + ka + 8);
            if (ka + 12 < IN_DIM) a3 = *(const float4*)(xr + ka + 12);
        }
        b0 = bgp[(BK >> 3) + scb];
    }

    int p = 0;
    for (int k0 = 0; k0 < KP1; k0 += BK) {
        __syncthreads();
        if (k0 + BK < KP1) {
            ushort av[16];
            av[0]=f2b(a0.x); av[1]=f2b(a0.y); av[2]=f2b(a0.z); av[3]=f2b(a0.w);
            av[4]=f2b(a1.x); av[5]=f2b(a1.y); av[6]=f2b(a1.z); av[7]=f2b(a1.w);
            av[8]=f2b(a2.x); av[9]=f2b(a2.y); av[10]=f2b(a2.z); av[11]=f2b(a2.w);
            av[12]=f2b(a3.x); av[13]=f2b(a3.y); av[14]=f2b(a3.z); av[15]=f2b(a3.w);
            *(uint4*)&As[1-p][sr][sc * 16 + 0] = *(const uint4*)&av[0];
            *(uint4*)&As[1-p][sr][sc * 16 + 8] = *(const uint4*)&av[8];
            *(uint4*)&Bs[1-p][sb][scb * 8]     = b0;
        }
        if (k0 + 2*BK < KP1) {
            const int ka = k0 + 2*BK + sc * 16;
            a0 = make_float4(0.f,0.f,0.f,0.f); a1 = a0; a2 = a0; a3 = a0;
            if (aval) {
                if (ka      < IN_DIM) a0 = *(const float4*)(xr + ka);
                if (ka + 4  < IN_DIM) a1 = *(const float4*)(xr + ka + 4);
                if (ka + 8  < IN_DIM) a2 = *(const float4*)(xr + ka + 8);
                if (ka + 12 < IN_DIM) a3 = *(const float4*)(xr + ka + 12);
            }
            b0 = bgp[((k0 + 2*BK) >> 3) + scb];
        }
#pragma unroll
        for (int s = 0; s < 2; ++s) {
            short8 af = *(const short8*)&As[p][wv * 16 + ln16][s * 32 + qd * 8];
#pragma unroll
            for (int nt = 0; nt < 2; ++nt) {
                short8 bf = *(const short8*)&Bs[p][nt * 16 + ln16][s * 32 + qd * 8];
                acc[nt] = __builtin_amdgcn_mfma_f32_16x16x32_bf16(af, bf, acc[nt], 0, 0, 0);
            }
        }
        p ^= 1;
    }

    const float* __restrict__ bias = fc1t + (size_t)L * FC1_STRIDE + (size_t)IN_DIM * HIDDEN + col0;
#pragma unroll
    for (int nt = 0; nt < 2; ++nt) {
        const int c = nt * 16 + ln16;
        const float bs = bias[c];
#pragma unroll
        for (int i = 0; i < 4; ++i) {
            const int r = wv * 16 + qd * 4 + i;
            if (r < nrows)
                h1b[(size_t)(pstart + r) * HIDDEN + col0 + c] = f2b(fmaxf(acc[nt][i] + bs, 0.f));
        }
    }
}

// =======================================================================
// fc2: 64-row x 32-col tiles (4 col-panels -> 192 blocks vs r0's 96).
// =======================================================================
__launch_bounds__(256)
__global__ void k_fc2m(const ushort* __restrict__ h1b, const ushort* __restrict__ w2b,
                       const float* __restrict__ fc2t, const int* __restrict__ meta,
                       float* __restrict__ out) {
    const int t = blockIdx.x;
    if (t >= meta[META_NTILES]) return;
    const int L      = meta[META_TILES + 3 * t + 0];
    const int pstart = meta[META_TILES + 3 * t + 1];
    const int nrows  = meta[META_TILES + 3 * t + 2];
    const int col0   = blockIdx.y * 32;
    const ushort* __restrict__ W = w2b + (size_t)L * STYLE * HIDDEN + (size_t)col0 * HIDDEN;

    __shared__ int rows[TB];
    __shared__ __align__(16) ushort As[2][64][72];
    __shared__ __align__(16) ushort Bs[2][32][72];

    const int tid = threadIdx.x;
    if (tid < TB) rows[tid] = (tid < nrows) ? meta[META_PERM + pstart + tid] : -1;
    __syncthreads();

    const int sr = tid >> 2, sc = tid & 3;
    const int sb = tid >> 3, scb = tid & 7;
    const int lane = tid & 63, wv = tid >> 6;
    const int qd = lane >> 4, ln16 = lane & 15;

    const bool aval = (sr < nrows);
    const uint4* __restrict__ agp = (const uint4*)(h1b + (size_t)(pstart + (aval ? sr : 0)) * HIDDEN);
    const uint4* __restrict__ bgp = (const uint4*)(W + (size_t)sb * HIDDEN);

    float4e acc[2] = {};
    uint4 a0, a1, b0;

    // chunk 0 -> buf 0
    a0 = make_uint4(0u,0u,0u,0u); a1 = a0;
    if (aval) { a0 = agp[sc * 2 + 0]; a1 = agp[sc * 2 + 1]; }
    b0 = bgp[scb];
    *(uint4*)&As[0][sr][sc * 16 + 0] = a0;
    *(uint4*)&As[0][sr][sc * 16 + 8] = a1;
    *(uint4*)&Bs[0][sb][scb * 8]     = b0;
    // chunk 1 -> regs
    {
        const int base = (BK >> 3) + sc * 2;
        a0 = make_uint4(0u,0u,0u,0u); a1 = a0;
        if (aval) { a0 = agp[base]; a1 = agp[base + 1]; }
        b0 = bgp[(BK >> 3) + scb];
    }

    int p = 0;
    for (int k0 = 0; k0 < HIDDEN; k0 += BK) {
        __syncthreads();
        if (k0 + BK < HIDDEN) {
            *(uint4*)&As[1-p][sr][sc * 16 + 0] = a0;
            *(uint4*)&As[1-p][sr][sc * 16 + 8] = a1;
            *(uint4*)&Bs[1-p][sb][scb * 8]     = b0;
        }
        if (k0 + 2*BK < HIDDEN) {
            const int base = ((k0 + 2*BK) >> 3) + sc * 2;
            a0 = make_uint4(0u,0u,0u,0u); a1 = a0;
            if (aval) { a0 = agp[base]; a1 = agp[base + 1]; }
            b0 = bgp[((k0 + 2*BK) >> 3) + scb];
        }
#pragma unroll
        for (int s = 0; s < 2; ++s) {
            short8 af = *(const short8*)&As[p][wv * 16 + ln16][s * 32 + qd * 8];
#pragma unroll
            for (int nt = 0; nt < 2; ++nt) {
                short8 bf = *(const short8*)&Bs[p][nt * 16 + ln16][s * 32 + qd * 8];
                acc[nt] = __builtin_amdgcn_mfma_f32_16x16x32_bf16(af, bf, acc[nt], 0, 0, 0);
            }
        }
        p ^= 1;
    }

    const float* __restrict__ bias = fc2t + (size_t)L * FC2_STRIDE + (size_t)HIDDEN * STYLE + col0;
#pragma unroll
    for (int nt = 0; nt < 2; ++nt) {
        const int c = nt * 16 + ln16;
        const float bs = bias[c];
#pragma unroll
        for (int i = 0; i < 4; ++i) {
            const int r = wv * 16 + qd * 4 + i;
            if (r < nrows) {
                const int orow = rows[r];
                out[(size_t)orow * STYLE + col0 + c] = 1.f / (1.f + __expf(-(acc[nt][i] + bs)));
            }
        }
    }
}

// ---------- fallback (ws too small): fused per-row, slow but correct ----------
__launch_bounds__(256)
__global__ void k_naive(const float* __restrict__ x, const int* __restrict__ m,
                        const float* __restrict__ fc1t, const float* __restrict__ fc2t,
                        float* __restrict__ out) {
    __shared__ float xs[IN_DIM];
    __shared__ float h1[HIDDEN];
    const int b = blockIdx.x, tid = threadIdx.x, L = m[b];
    for (int k = tid; k < IN_DIM; k += 256) xs[k] = x[(size_t)b * IN_DIM + k];
    __syncthreads();
    const float* __restrict__ W1 = fc1t + (size_t)L * FC1_STRIDE;
    for (int j = tid; j < HIDDEN; j += 256) {
        float acc = W1[(size_t)IN_DIM * HIDDEN + j];
        for (int k = 0; k < IN_DIM; ++k) acc = fmaf(xs[k], W1[(size_t)k * HIDDEN + j], acc);
        h1[j] = fmaxf(acc, 0.f);
    }
    __syncthreads();
    const float* __restrict__ W2 = fc2t + (size_t)L * FC2_STRIDE;
    for (int j = tid; j < STYLE; j += 256) {
        float acc = W2[(size_t)HIDDEN * STYLE + j];
        for (int k = 0; k < HIDDEN; ++k) acc = fmaf(h1[k], W2[(size_t)k * STYLE + j], acc);
        out[(size_t)b * STYLE + j] = 1.f / (1.f + __expf(-acc));
    }
}

extern "C" void kernel_launch(void* const* d_in, const int* in_sizes, int n_in,
                              void* d_out, int out_size, void* d_ws, size_t ws_size,
                              hipStream_t stream) {
    const float* x    = (const float*)d_in[0];
    const int*   m    = (const int*)d_in[1];
    const float* fc1t = (const float*)d_in[2];
    const float* fc2t = (const float*)d_in[3];
    float* out = (float*)d_out;

    if (ws_size >= WS_NEED) {
        int*    meta = (int*)d_ws;
        ushort* w1b  = (ushort*)((char*)d_ws + W1B_OFF);
        ushort* w2b  = (ushort*)((char*)d_ws + W2B_OFF);
        ushort* h1b  = (ushort*)((char*)d_ws + H1B_OFF);

        k_prep<<<1 + W1_BLOCKS + W2_BLOCKS, 256, 0, stream>>>(m, fc1t, fc2t, meta, w1b, w2b);
        k_fc1m<<<dim3(MAX_TILES, HIDDEN / 32), 256, 0, stream>>>(x, w1b, fc1t, meta, h1b);
        k_fc2m<<<dim3(MAX_TILES, STYLE / 32), 256, 0, stream>>>(h1b, w2b, fc2t, meta, out);
    } else {
        k_naive<<<BATCH, 256, 0, stream>>>(x, m, fc1t, fc2t, out);
    }
}